// Round 3
// baseline (1812.431 us; speedup 1.0000x reference)
//
#include <hip/hip_runtime.h>

// Mixed2DEpsNetwork: G=2000 graphs x 16 nodes, H=128, 6 EGNN layers + edge MLP.
// R3: conflict-free LDS discipline — producers write row-major (stride-1),
// GEMMs read transposed buffers via wave-uniform b128 broadcasts, and dedicated
// bank-balanced float4 transpose passes bridge the two layouts.

#define G_GRAPHS 2000
#define NPG 16
#define HID 128
#define FDIM 28
#define NLAYER 6
#define NNODES 32000
#define EL_PER_G 32
#define EG_PER_G 240
#define EL_TOT (G_GRAPHS*EL_PER_G)
#define EG_TOT (G_GRAPHS*EG_PER_G)
#define TMAX 32   // bond-type table size (actual types are 0..21)
#define HTP 20    // h_t row pad: float4-aligned AND bank-balanced for f4 passes

__device__ __forceinline__ float silu_f(float x) {
    return x / (1.0f + __expf(-x));
}
__device__ __forceinline__ int clampT(int t) {
    return t < 0 ? 0 : (t > TMAX-1 ? TMAX-1 : t);
}

// bondA[l][t][c] = bond_emb[t] @ Wl[l,256:384] + bl[l]   (e_r contribution, bl folded)
// bondB[l][t][c] = bond_emb[t] @ Wl[l,384:512]           (e_p contribution)
__global__ void __launch_bounds__(HID) k_tab_bond(
    const float* __restrict__ bond_emb, const float* __restrict__ Wl,
    const float* __restrict__ bl, float* __restrict__ bondA, float* __restrict__ bondB)
{
    int l = blockIdx.x >> 5;
    int t = blockIdx.x & 31;
    int c = threadIdx.x;
    const float* WlL = Wl + (size_t)l*512*HID;
    float accA = bl[l*HID + c];
    float accB = 0.f;
    #pragma unroll 4
    for (int k = 0; k < HID; k++) {
        float e = bond_emb[t*HID + k];
        accA = fmaf(e, WlL[(256+k)*HID + c], accA);
        accB = fmaf(e, WlL[(384+k)*HID + c], accB);
    }
    bondA[(l*TMAX + t)*HID + c] = accA;
    bondB[(l*TMAX + t)*HID + c] = accB;
}

// pairT[tr][tp][c] = (bond_emb[tr]*bond_emb[tp]) @ W0[128:256] + b0  (b0 folded)
__global__ void __launch_bounds__(HID) k_tab_pair(
    const float* __restrict__ bond_emb, const float* __restrict__ W0,
    const float* __restrict__ b0, float* __restrict__ pairT)
{
    int tr = blockIdx.x >> 5;
    int tp = blockIdx.x & 31;
    int c = threadIdx.x;
    float acc = b0[c];
    #pragma unroll 4
    for (int k = 0; k < HID; k++)
        acc = fmaf(bond_emb[tr*HID + k] * bond_emb[tp*HID + k], W0[(HID+k)*HID + c], acc);
    pairT[(size_t)blockIdx.x*HID + c] = acc;
}

// h[n] = concat(atom_emb[at] + r@W, (p-r)@W)
__global__ void __launch_bounds__(256) k_init_h(
    const int* __restrict__ atom_type, const float* __restrict__ r_feat,
    const float* __restrict__ p_feat, const float* __restrict__ atom_emb,
    const float* __restrict__ afW, float* __restrict__ h)
{
    int n = blockIdx.x*4 + (threadIdx.x >> 6);
    int j = threadIdx.x & 63;
    int at = atom_type[n];
    float accr = 0.f, accp = 0.f;
    #pragma unroll
    for (int k = 0; k < FDIM; k++) {
        float w = afW[k*64 + j];
        accr = fmaf(r_feat[n*FDIM + k], w, accr);
        accp = fmaf(p_feat[n*FDIM + k], w, accp);
    }
    h[n*HID + j]      = atom_emb[at*64 + j] + accr;
    h[n*HID + 64 + j] = accp - accr;
}

// One block per graph; all 6 layers fused.
__global__ void __launch_bounds__(256) k_encoder(
    const float* __restrict__ pos,
    const int* __restrict__ eil, const int* __restrict__ etr, const int* __restrict__ etp,
    const int* __restrict__ eig,
    const float* __restrict__ Wg, const float* __restrict__ bg,
    const float* __restrict__ Wl,
    const float* __restrict__ Wn, const float* __restrict__ bn,
    const float* __restrict__ bondA, const float* __restrict__ bondB,
    float* __restrict__ h)
{
    __shared__ __align__(16) float h_t[HID][HTP];     // [col][node], pad 20: 10KB
    __shared__ __align__(16) float agg_t[HID][NPG];   // [col][node]: 8KB
    __shared__ __align__(16) float A_s[NPG][HID];     // row-major (also agg staging)
    __shared__ __align__(16) float B_s[NPG][HID];     // row-major (also uo staging)
    __shared__ __align__(16) float Al_s[NPG][HID];
    __shared__ __align__(16) float Bl_s[NPG][HID];
    __shared__ float d2m[NPG][NPG];
    __shared__ unsigned msk[NPG];
    __shared__ float px[NPG], py[NPG], pz[NPG];
    __shared__ int llist[NPG][2];
    __shared__ int lcnt[NPG];
    __shared__ int lsrc_s[EL_PER_G], ltr_s[EL_PER_G], ltp_s[EL_PER_G];

    const int g = blockIdx.x;
    const int tid = threadIdx.x;
    const int u  = tid & 63;     // column pair: cols 2u, 2u+1 (GEMM phases)
    const int ng = tid >> 6;     // node group: nodes 4ng..4ng+3 (GEMM phases)
    const int c  = tid & 127;    // column (phase-2 / transpose passes)
    const int dh = tid >> 7;     // half index (phase-2 / transpose passes)

    // ---- initial: coalesced load h into row-major A_s; topology build
    for (int idx = tid; idx < NPG*HID; idx += 256)
        A_s[idx >> 7][idx & 127] = h[(size_t)g*NPG*HID + idx];
    if (tid < NPG) {
        px[tid] = pos[(g*NPG + tid)*3 + 0];
        py[tid] = pos[(g*NPG + tid)*3 + 1];
        pz[tid] = pos[(g*NPG + tid)*3 + 2];
        lcnt[tid] = 0; msk[tid] = 0u;
    }
    __syncthreads();
    if (tid < EG_PER_G) {
        int e = g*EG_PER_G + tid;
        int s = eig[e] - g*NPG;
        int d = eig[EG_TOT + e] - g*NPG;
        float dx = px[s]-px[d], dy = py[s]-py[d], dz = pz[s]-pz[d];
        d2m[d][s] = dx*dx + dy*dy + dz*dz;
        atomicOr(&msk[d], 1u << s);
    }
    if (tid < EL_PER_G) {
        int e = g*EL_PER_G + tid;
        int s = eil[e] - g*NPG;
        int d = eil[EL_TOT + e] - g*NPG;
        lsrc_s[tid] = s;
        ltr_s[tid] = clampT(etr[e]);
        ltp_s[tid] = clampT(etp[e]);
        int slot = atomicAdd(&lcnt[d], 1);
        if (slot < 2) llist[d][slot] = tid;
    }
    // transpose A_s -> h_t (reads stride-1; f4 writes bank-balanced at pad 20)
    #pragma unroll
    for (int qq = dh; qq < 4; qq += 2) {
        float4 v;
        v.x = A_s[4*qq+0][c]; v.y = A_s[4*qq+1][c];
        v.z = A_s[4*qq+2][c]; v.w = A_s[4*qq+3][c];
        *(float4*)&h_t[c][4*qq] = v;
    }
    __syncthreads();

    for (int l = 0; l < NLAYER; l++) {
        const float* WgL = Wg + (size_t)l*257*HID;
        const float* WlL = Wl + (size_t)l*512*HID;
        const float* WnL = Wn + (size_t)l*256*HID;

        // ---- phase 1: A=h@Wg0, B=h@Wg1+bg, Al=h@Wl0, Bl=h@Wl1 (row-major out)
        {
            const float2* wg0 = (const float2*)WgL + u;
            const float2* wg1 = (const float2*)(WgL + 128*HID) + u;
            const float2* wl0 = (const float2*)WlL + u;
            const float2* wl1 = (const float2*)(WlL + 128*HID) + u;
            float2 bgv = *(const float2*)&bg[l*HID + 2*u];
            float2 aA[4], aB[4], aAl[4], aBl[4];
            #pragma unroll
            for (int i = 0; i < 4; i++) {
                aA[i]  = make_float2(0.f, 0.f);
                aB[i]  = bgv;
                aAl[i] = make_float2(0.f, 0.f);
                aBl[i] = make_float2(0.f, 0.f);
            }
            #pragma unroll 4
            for (int k = 0; k < HID; k++) {
                float2 w0 = wg0[k*64];
                float2 w1 = wg1[k*64];
                float2 w2 = wl0[k*64];
                float2 w3 = wl1[k*64];
                float4 hv = *(const float4*)&h_t[k][ng*4];   // wave-uniform broadcast
                float hh[4] = {hv.x, hv.y, hv.z, hv.w};
                #pragma unroll
                for (int i = 0; i < 4; i++) {
                    aA[i].x  = fmaf(hh[i], w0.x, aA[i].x);  aA[i].y  = fmaf(hh[i], w0.y, aA[i].y);
                    aB[i].x  = fmaf(hh[i], w1.x, aB[i].x);  aB[i].y  = fmaf(hh[i], w1.y, aB[i].y);
                    aAl[i].x = fmaf(hh[i], w2.x, aAl[i].x); aAl[i].y = fmaf(hh[i], w2.y, aAl[i].y);
                    aBl[i].x = fmaf(hh[i], w3.x, aBl[i].x); aBl[i].y = fmaf(hh[i], w3.y, aBl[i].y);
                }
            }
            #pragma unroll
            for (int i = 0; i < 4; i++) {
                int n = ng*4 + i;
                *(float2*)&A_s[n][2*u]  = aA[i];    // stride-2 lanes: conflict-free
                *(float2*)&B_s[n][2*u]  = aB[i];
                *(float2*)&Al_s[n][2*u] = aAl[i];
                *(float2*)&Bl_s[n][2*u] = aBl[i];
            }
        }
        __syncthreads();

        // ---- phase 2: messages + per-dest accumulation (into registers)
        float accv[8];
        {
            float wgd = WgL[256*HID + c];
            const float* bA = bondA + (size_t)l*TMAX*HID;
            const float* bB = bondB + (size_t)l*TMAX*HID;
            float Areg[NPG];
            #pragma unroll
            for (int s = 0; s < NPG; s++) Areg[s] = A_s[s][c];   // stride-1
            #pragma unroll
            for (int dd = 0; dd < 8; dd++) {
                int d = dh*8 + dd;
                float base = B_s[d][c];          // bg folded
                unsigned m = msk[d];             // wave-uniform
                float acc = 0.f;
                #pragma unroll
                for (int s = 0; s < NPG; s++) {
                    if (m & (1u << s)) {
                        float x = Areg[s] + fmaf(d2m[d][s], wgd, base);
                        acc += silu_f(x);
                    }
                }
                float blb = Bl_s[d][c];
                int lc2 = lcnt[d] < 2 ? lcnt[d] : 2;
                for (int i2 = 0; i2 < lc2; i2++) {
                    int ke = llist[d][i2];
                    float x = Al_s[lsrc_s[ke]][c] + blb
                            + bA[ltr_s[ke]*HID + c] + bB[ltp_s[ke]*HID + c];
                    acc += silu_f(x);
                }
                accv[dd] = acc;
            }
        }
        __syncthreads();   // all A_s/B_s/Al_s/Bl_s reads done
        #pragma unroll
        for (int dd = 0; dd < 8; dd++)
            A_s[dh*8 + dd][c] = accv[dd];        // agg staging, stride-1
        __syncthreads();
        // transpose A_s -> agg_t
        #pragma unroll
        for (int qq = dh; qq < 4; qq += 2) {
            float4 v;
            v.x = A_s[4*qq+0][c]; v.y = A_s[4*qq+1][c];
            v.z = A_s[4*qq+2][c]; v.w = A_s[4*qq+3][c];
            *(float4*)&agg_t[c][4*qq] = v;
        }
        __syncthreads();

        // ---- phase 3: uo = silu([h,agg]@Wn + bn)  (staged to B_s)
        {
            const float2* wn0 = (const float2*)WnL + u;
            const float2* wn1 = (const float2*)(WnL + 128*HID) + u;
            float2 bnv = *(const float2*)&bn[l*HID + 2*u];
            float2 acc2[4];
            #pragma unroll
            for (int i = 0; i < 4; i++) acc2[i] = bnv;
            #pragma unroll 4
            for (int k = 0; k < HID; k++) {
                float2 w0 = wn0[k*64];
                float2 w1 = wn1[k*64];
                float4 hv = *(const float4*)&h_t[k][ng*4];    // broadcast
                float4 av = *(const float4*)&agg_t[k][ng*4];  // broadcast
                float hh[4] = {hv.x, hv.y, hv.z, hv.w};
                float aa[4] = {av.x, av.y, av.z, av.w};
                #pragma unroll
                for (int i = 0; i < 4; i++) {
                    acc2[i].x = fmaf(hh[i], w0.x, acc2[i].x);
                    acc2[i].y = fmaf(hh[i], w0.y, acc2[i].y);
                    acc2[i].x = fmaf(aa[i], w1.x, acc2[i].x);
                    acc2[i].y = fmaf(aa[i], w1.y, acc2[i].y);
                }
            }
            #pragma unroll
            for (int i = 0; i < 4; i++) {
                float2 uo;
                uo.x = silu_f(acc2[i].x);
                uo.y = silu_f(acc2[i].y);
                *(float2*)&B_s[ng*4 + i][2*u] = uo;   // B_s dead since phase 2
            }
        }
        __syncthreads();   // uo staged AND all h_t reads done
        // residual: h_t += B_s^T  (f4 RMW bank-balanced; B_s reads stride-1)
        #pragma unroll
        for (int qq = dh; qq < 4; qq += 2) {
            float4 v = *(const float4*)&h_t[c][4*qq];
            v.x += B_s[4*qq+0][c]; v.y += B_s[4*qq+1][c];
            v.z += B_s[4*qq+2][c]; v.w += B_s[4*qq+3][c];
            *(float4*)&h_t[c][4*qq] = v;
        }
        __syncthreads();
    }

    // ---- final: transpose h_t -> A_s, coalesced store
    #pragma unroll
    for (int qq = dh; qq < 4; qq += 2) {
        float4 v = *(const float4*)&h_t[c][4*qq];
        A_s[4*qq+0][c] = v.x; A_s[4*qq+1][c] = v.y;
        A_s[4*qq+2][c] = v.z; A_s[4*qq+3][c] = v.w;
    }
    __syncthreads();
    for (int idx = tid; idx < NPG*HID; idx += 256)
        h[(size_t)g*NPG*HID + idx] = A_s[idx >> 7][idx & 127];
}

// Edge MLP: x0=relu((h[s]*h[d])@W00 + pairT); x1=relu(x0@W1+b1); out=x1@W2+b2
__global__ void __launch_bounds__(256) k_mlp(
    const float* __restrict__ h,
    const int* __restrict__ eig, const int* __restrict__ egr, const int* __restrict__ egp,
    const float* __restrict__ pairT, const float* __restrict__ W0,
    const float* __restrict__ W1, const float* __restrict__ b1,
    const float* __restrict__ W2, const float* __restrict__ b2,
    float* __restrict__ out)
{
    __shared__ __align__(16) float h_s[NPG][HID];      // row-major
    __shared__ __align__(16) float stage[NPG][HID];    // row-major staging
    __shared__ __align__(16) float prod_t[HID][HTP];   // [col][edge] pad 20
    __shared__ __align__(16) float x0_t[HID][HTP];     // [col][edge] pad 20
    __shared__ int sgl[EG_PER_G], dgl[EG_PER_G], pidx[EG_PER_G];

    const int g = blockIdx.x;
    const int tid = threadIdx.x;

    for (int idx = tid; idx < NPG*HID; idx += 256)
        h_s[idx >> 7][idx & 127] = h[(size_t)g*NPG*HID + idx];
    if (tid < EG_PER_G) {
        int e = g*EG_PER_G + tid;
        sgl[tid] = eig[e] - g*NPG;
        dgl[tid] = eig[EG_TOT + e] - g*NPG;
        pidx[tid] = clampT(egr[e])*TMAX + clampT(egp[e]);
    }
    __syncthreads();

    const int u  = tid & 63;    // x0: col pair 2u,2u+1 ; x1: col j=u
    const int eg = tid >> 6;    // edge subgroup of 4
    const int kk = tid & 127;   // staging col
    const int eh = tid >> 7;    // staging half
    const float b2v = b2[0];
    const float b1v = b1[u];
    const float w2v = W2[u];

    for (int e0 = 0; e0 < EG_PER_G; e0 += 16) {
        // ---- prod into row-major stage (stride-1 writes)
        #pragma unroll
        for (int i = 0; i < 8; i++) {
            int e = e0 + eh*8 + i;
            stage[eh*8 + i][kk] = h_s[sgl[e]][kk] * h_s[dgl[e]][kk];
        }
        __syncthreads();
        // transpose stage -> prod_t
        #pragma unroll
        for (int qq = eh; qq < 4; qq += 2) {
            float4 v;
            v.x = stage[4*qq+0][kk]; v.y = stage[4*qq+1][kk];
            v.z = stage[4*qq+2][kk]; v.w = stage[4*qq+3][kk];
            *(float4*)&prod_t[kk][4*qq] = v;
        }
        __syncthreads();

        // ---- x0 GEMM: 16 edges x 128 cols over k=128
        float2 acc[4];
        #pragma unroll
        for (int i = 0; i < 4; i++)
            acc[i] = ((const float2*)(pairT + (size_t)pidx[e0 + eg*4 + i]*HID))[u];
        {
            const float2* w0p = (const float2*)W0 + u;
            #pragma unroll 4
            for (int k = 0; k < HID; k++) {
                float2 w = w0p[k*64];
                float4 pv = *(const float4*)&prod_t[k][eg*4];  // broadcast
                float pp[4] = {pv.x, pv.y, pv.z, pv.w};
                #pragma unroll
                for (int i = 0; i < 4; i++) {
                    acc[i].x = fmaf(pp[i], w.x, acc[i].x);
                    acc[i].y = fmaf(pp[i], w.y, acc[i].y);
                }
            }
        }
        #pragma unroll
        for (int i = 0; i < 4; i++) {
            float2 xo;
            xo.x = fmaxf(acc[i].x, 0.f);
            xo.y = fmaxf(acc[i].y, 0.f);
            *(float2*)&stage[eg*4 + i][2*u] = xo;   // stage dead after transpose
        }
        __syncthreads();
        // transpose stage -> x0_t
        #pragma unroll
        for (int qq = eh; qq < 4; qq += 2) {
            float4 v;
            v.x = stage[4*qq+0][kk]; v.y = stage[4*qq+1][kk];
            v.z = stage[4*qq+2][kk]; v.w = stage[4*qq+3][kk];
            *(float4*)&x0_t[kk][4*qq] = v;
        }
        __syncthreads();

        // ---- x1 GEMM + final dot
        float y[4] = {b1v, b1v, b1v, b1v};
        {
            const float* w1p = W1 + u;
            #pragma unroll 4
            for (int k = 0; k < HID; k++) {
                float wv = w1p[k*64];
                float4 xv = *(const float4*)&x0_t[k][eg*4];    // broadcast
                y[0] = fmaf(xv.x, wv, y[0]);
                y[1] = fmaf(xv.y, wv, y[1]);
                y[2] = fmaf(xv.z, wv, y[2]);
                y[3] = fmaf(xv.w, wv, y[3]);
            }
        }
        #pragma unroll
        for (int i = 0; i < 4; i++) {
            float v = fmaxf(y[i], 0.f) * w2v;
            #pragma unroll
            for (int off = 32; off; off >>= 1)
                v += __shfl_xor(v, off, 64);
            if (u == 0) out[(size_t)g*EG_PER_G + e0 + eg*4 + i] = v + b2v;
        }
        // no barrier needed: next batch's stage writes don't race x1's x0_t reads
        __syncthreads();   // (kept for safety: uniform barrier count per batch)
    }
}

extern "C" void kernel_launch(void* const* d_in, const int* in_sizes, int n_in,
                              void* d_out, int out_size, void* d_ws, size_t ws_size,
                              hipStream_t stream) {
    const int*   atom_type = (const int*)  d_in[0];
    const float* r_feat    = (const float*)d_in[1];
    const float* p_feat    = (const float*)d_in[2];
    const float* pos       = (const float*)d_in[3];
    const int*   eil       = (const int*)  d_in[4];
    const int*   etr       = (const int*)  d_in[5];
    const int*   etp       = (const int*)  d_in[6];
    const int*   eig       = (const int*)  d_in[7];
    const int*   egr       = (const int*)  d_in[8];
    const int*   egp       = (const int*)  d_in[9];
    const float* bond_emb  = (const float*)d_in[10];
    const float* atom_emb  = (const float*)d_in[11];
    const float* afW       = (const float*)d_in[12];
    const float* Wl        = (const float*)d_in[13];
    const float* bl        = (const float*)d_in[14];
    const float* Wg        = (const float*)d_in[15];
    const float* bg        = (const float*)d_in[16];
    const float* Wn        = (const float*)d_in[17];
    const float* bn        = (const float*)d_in[18];
    const float* W0        = (const float*)d_in[19];
    const float* b0        = (const float*)d_in[20];
    const float* W1        = (const float*)d_in[21];
    const float* b1        = (const float*)d_in[22];
    const float* W2        = (const float*)d_in[23];
    const float* b2        = (const float*)d_in[24];

    float* h     = (float*)d_ws;
    float* bondA = h + (size_t)NNODES*HID;
    float* bondB = bondA + (size_t)NLAYER*TMAX*HID;
    float* pairT = bondB + (size_t)NLAYER*TMAX*HID;
    float* out   = (float*)d_out;

    k_tab_bond<<<dim3(NLAYER*TMAX), dim3(HID), 0, stream>>>(bond_emb, Wl, bl, bondA, bondB);
    k_tab_pair<<<dim3(TMAX*TMAX),  dim3(HID), 0, stream>>>(bond_emb, W0, b0, pairT);
    k_init_h  <<<dim3(NNODES/4),   dim3(256), 0, stream>>>(atom_type, r_feat, p_feat, atom_emb, afW, h);
    k_encoder <<<dim3(G_GRAPHS),   dim3(256), 0, stream>>>(pos, eil, etr, etp, eig,
                                                           Wg, bg, Wl, Wn, bn, bondA, bondB, h);
    k_mlp     <<<dim3(G_GRAPHS),   dim3(256), 0, stream>>>(h, eig, egr, egp, pairT,
                                                           W0, W1, b1, W2, b2, out);
}